// Round 3
// baseline (56325.201 us; speedup 1.0000x reference)
//
#include <hip/hip_runtime.h>
#include <stdint.h>
#include <stdio.h>

// ---------------------------------------------------------------------------
// DilatedSparseRnnStack, round 3: round-2 design with two fixes:
//  (1) weight fragment per-wave base offset was off by 64x (waves 1-3 read
//      wrong weights -> absmax 0.27). Now w*16*KT*1024 bytes.
//  (2) GEMM loop order k-outer/(g,q)-inner: 15-16 independent MFMA chains
//      between accumulator reuses (was k-inner = dependent chain, ~16cyc/MFMA
//      exposed at 1 wave/SIMD).
// Design: 64 WGs x 16 batch rows, zero inter-WG communication. Weights
// pre-swizzled to MFMA B-fragment order, streamed from per-XCD L2 each step.
// h rings + out ping-pong in LDS; prevC in VGPRs; dilated C rings in global
// ws (non-temporal, keeps L2 for weights). Layer0 (dil=1) alpha-gate GEMM
// skipped (weightedC == prevC identically).
// ---------------------------------------------------------------------------

typedef __attribute__((ext_vector_type(8))) short short8;
typedef __attribute__((ext_vector_type(4))) float f32x4;

#define DEVINL static __device__ __forceinline__

constexpr int TT = 256, BB = 1024, NO = 8;

constexpr int KLa[4]  = {320, 384, 448, 384};
constexpr int KTa[4]  = {10, 12, 14, 12};      // K/32 tiles
constexpr int DILa[4] = {1, 3, 6, 12};

// weight fragment counts (frag = 64 lanes x 16B = 1 KB per (ntile,ktile))
constexpr int LFRAG[4] = {0, 40960, 90112, 147456};
constexpr int NFRAG_TOT = 196608;              // x16B = 3,145,728 bytes

// LDS layout (bytes). h ring slot = 4 ktiles x 64 lanes x 16B = 4096.
constexpr int HOFF[4]  = {0, 8192, 24576, 53248};   // P = dil+1 slots each
constexpr int HEND     = 106496;                     // 26 slots total
constexpr int O0_OFF   = 106496;
constexpr int O1_OFF   = 110592;
constexpr int WOUT_OFF = 114688;                     // 8x128 fp32
constexpr int BOUT_OFF = 118784;
constexpr int LDS_BYTES = 118816;

// workspace layout (bytes)
constexpr size_t WSWZ_OFF   = 0;                     // 3,145,728
constexpr size_t CRING_OFF  = 4u * 1024 * 1024;
constexpr size_t CR_WG      = 344064;                // per-WG: 3+6+12 slots x 16KB
constexpr size_t CROFF[4]   = {0, 0, 49152, 147456}; // L1,L2,L3 rings (L0 none)
constexpr size_t WS_NEED    = CRING_OFF + 64 * CR_WG; // 26,214,400

template <int N> struct IC { static constexpr int value = N; };

DEVINL unsigned short f2bf(float f) {        // RNE fp32 -> bf16
  union { float f; uint32_t u; } v; v.f = f;
  return (unsigned short)((v.u + 0x7FFFu + ((v.u >> 16) & 1u)) >> 16);
}
DEVINL float bf2f(unsigned short h) {
  union { uint32_t u; float f; } v; v.u = ((uint32_t)h) << 16;
  return v.f;
}
DEVINL float sigm(float x)  { return 1.0f / (1.0f + __expf(-x)); }
DEVINL float tanh_(float x) { return 1.0f - 2.0f / (__expf(2.0f * x) + 1.0f); }
DEVINL f32x4 zero_f4() { f32x4 v; for (int i = 0; i < 4; i++) v[i] = 0.f; return v; }

DEVINL f32x4 mfma16(short8 a, short8 b, f32x4 c) {
  return __builtin_amdgcn_mfma_f32_16x16x32_bf16(a, b, c, 0, 0, 0);
}

DEVINL short8 ld8f_nt(const float* p) {      // 8 fp32 (nt) -> bf16x8 fragment
  const f32x4 u0 = __builtin_nontemporal_load((const f32x4*)p);
  const f32x4 u1 = __builtin_nontemporal_load((const f32x4*)(p + 4));
  short8 r;
  r[0] = (short)f2bf(u0[0]); r[1] = (short)f2bf(u0[1]);
  r[2] = (short)f2bf(u0[2]); r[3] = (short)f2bf(u0[3]);
  r[4] = (short)f2bf(u1[0]); r[5] = (short)f2bf(u1[1]);
  r[6] = (short)f2bf(u1[2]); r[7] = (short)f2bf(u1[3]);
  return r;
}

// ---------------------------------------------------------------------------
// prep: fp32 weights -> bf16 MFMA B-fragment order.
// frag idx = LFRAG[L] + (((w*4+g)*4+q)*KT + k)*64 + lane
// element  = W_L[g*256 + w*64 + q*16 + (lane&15)][k*32 + (lane>>4)*8 + j]
// ---------------------------------------------------------------------------
__global__ void __launch_bounds__(256)
prep_weights(const float* __restrict__ W0, const float* __restrict__ W1,
             const float* __restrict__ W2, const float* __restrict__ W3,
             unsigned short* __restrict__ wz)
{
  int idx = blockIdx.x * 256 + threadIdx.x;
  if (idx >= NFRAG_TOT) return;
  int L, r;
  if (idx < LFRAG[1]) { L = 0; r = idx; }
  else if (idx < LFRAG[2]) { L = 1; r = idx - LFRAG[1]; }
  else if (idx < LFRAG[3]) { L = 2; r = idx - LFRAG[2]; }
  else { L = 3; r = idx - LFRAG[3]; }
  const float* Wl = (L == 0) ? W0 : (L == 1) ? W1 : (L == 2) ? W2 : W3;
  const int KT = KTa[L], K = KLa[L];
  const int lane = r & 63; r >>= 6;
  const int k = r % KT; r /= KT;
  const int q = r & 3; r >>= 2;
  const int g = r & 3; r >>= 2;
  const int w = r;
  const int n  = g * 256 + w * 64 + q * 16 + (lane & 15);
  const int kk = k * 32 + (lane >> 4) * 8;
  const float* p = Wl + (size_t)n * K + kk;
  const f32x4 u0 = *(const f32x4*)p;
  const f32x4 u1 = *(const f32x4*)(p + 4);
  short8 o;
  o[0] = (short)f2bf(u0[0]); o[1] = (short)f2bf(u0[1]);
  o[2] = (short)f2bf(u0[2]); o[3] = (short)f2bf(u0[3]);
  o[4] = (short)f2bf(u1[0]); o[5] = (short)f2bf(u1[1]);
  o[6] = (short)f2bf(u1[2]); o[7] = (short)f2bf(u1[3]);
  ((short8*)wz)[idx] = o;
}

// ---------------------------------------------------------------------------
// main kernel
// ---------------------------------------------------------------------------
__global__ void __launch_bounds__(256, 1)
rnn_main(const float* __restrict__ x,
         const float* __restrict__ b0, const float* __restrict__ b1,
         const float* __restrict__ b2, const float* __restrict__ b3,
         const float* __restrict__ Wout, const float* __restrict__ bout,
         const unsigned short* __restrict__ wswz,
         char* __restrict__ cring_all,
         float* __restrict__ yout)
{
  extern __shared__ char smem[];
  float* woutl = (float*)(smem + WOUT_OFF);
  float* boutl = (float*)(smem + BOUT_OFF);

  const int wg = blockIdx.x;          // 0..63, owns batch rows wg*16..+15
  const int tid = threadIdx.x;
  const int w = tid >> 6, lane = tid & 63, lm = lane & 15, quad = lane >> 4;

  // ---- init LDS: zero h rings, load Wout/bout ----
  for (int i = tid; i < HEND / 16; i += 256) {
    *(f32x4*)(smem + i * 16) = zero_f4();
  }
  for (int i = tid; i < 8 * 128; i += 256) woutl[i] = Wout[i];
  if (tid < 8) boutl[tid] = bout[tid];

  // ---- biases in VGPRs: biasv[L][g*4+q] (forget gate gets its +1 here) ----
  float biasv[4][16];
  {
    const float* bsrc[4] = {b0, b1, b2, b3};
#pragma unroll
    for (int L = 0; L < 4; L++)
#pragma unroll
      for (int g = 0; g < 4; g++)
#pragma unroll
        for (int q = 0; q < 4; q++)
          biasv[L][g * 4 + q] =
              bsrc[L][g * 256 + w * 64 + q * 16 + lm] + (g == 0 ? 1.0f : 0.0f);
  }
  __syncthreads();

  f32x4 pC[4][4];                     // prevC: [layer][q] over 4 rows (r)
#pragma unroll
  for (int L = 0; L < 4; L++)
#pragma unroll
    for (int q = 0; q < 4; q++) pC[L][q] = zero_f4();

  char* crwg = cring_all + (size_t)wg * CR_WG;
  const int lof = lane * 16;

  for (int t = 0; t < TT; t++) {
    // x fragments for this step (k 0..31, 32..63), reused by L0 and L2
    const float* xp = x + ((size_t)t * BB + wg * 16 + lm) * 64 + quad * 8;
    const short8 xf0 = ld8f_nt(xp);
    const short8 xf1 = ld8f_nt(xp + 32);

    auto do_layer = [&](auto Lc) {
      constexpr int L  = decltype(Lc)::value;
      constexpr int KT = KTa[L];
      constexpr int DL = DILa[L];
      constexpr int P  = DL + 1;

      __syncthreads();   // prior layer's LDS writes visible; protects ping-pong

      // ---- A fragments (registers) ----
      const int psl = (t >= 1) ? (t - 1) % P : P - 1;
      const int dsl = (t >= DL) ? (t - DL) % P : psl;
      const char* pHb = smem + HOFF[L] + psl * 4096;
      const char* dHb = smem + HOFF[L] + dsl * 4096;
      const char* oBb = smem + ((L & 1) ? O0_OFF : O1_OFF);  // reads outbuf[(L-1)&1]

      short8 aF[KT];
      if constexpr (L == 0) {
        aF[0] = xf0; aF[1] = xf1;
#pragma unroll
        for (int i = 0; i < 4; i++) {
          aF[2 + i] = *(const short8*)(pHb + i * 1024 + lof);
          aF[6 + i] = *(const short8*)(dHb + i * 1024 + lof);
        }
      } else if constexpr (L == 2) {
#pragma unroll
        for (int i = 0; i < 4; i++) aF[i] = *(const short8*)(oBb + i * 1024 + lof);
        aF[4] = xf0; aF[5] = xf1;
#pragma unroll
        for (int i = 0; i < 4; i++) {
          aF[6 + i]  = *(const short8*)(pHb + i * 1024 + lof);
          aF[10 + i] = *(const short8*)(dHb + i * 1024 + lof);
        }
      } else {
#pragma unroll
        for (int i = 0; i < 4; i++) {
          aF[i]     = *(const short8*)(oBb + i * 1024 + lof);
          aF[4 + i] = *(const short8*)(pHb + i * 1024 + lof);
          aF[8 + i] = *(const short8*)(dHb + i * 1024 + lof);
        }
      }

      // ---- dilated-C prefetch (private global ring, non-temporal) ----
      f32x4 dC[4];
#pragma unroll
      for (int q = 0; q < 4; q++) dC[q] = zero_f4();
      char* crp = nullptr;
      if constexpr (L > 0) {
        crp = crwg + CROFF[L] + (size_t)(t % DL) * 16384 + tid * 64;
        if (t >= DL) {
#pragma unroll
          for (int q = 0; q < 4; q++)
            dC[q] = __builtin_nontemporal_load((const f32x4*)(crp + q * 16));
        }
      }

      // ---- GEMM: acc[g][q] = xh(16xK) @ W(16xK)^T per n-tile ----
      // k OUTER, (g,q) inner: 15-16 independent MFMA chains between
      // accumulator reuses -> throughput-bound issue at 1 wave/SIMD.
      f32x4 acc[4][4];
#pragma unroll
      for (int g = 0; g < 4; g++)
#pragma unroll
        for (int q = 0; q < 4; q++) acc[g][q] = zero_f4();

      // frag byte offset = (LFRAG[L] + ((w*16+g*4+q)*KT + k)*64 + lane)*16
      const char* wb8 = (const char*)wswz + (size_t)LFRAG[L] * 16 +
                        (size_t)(w * 16 * KT) * 1024 + lof;
#pragma unroll
      for (int k = 0; k < KT; k++) {
        const short8 af = aF[k];
#pragma unroll
        for (int g = 0; g < 4; g++) {
          if (L == 0 && g == 2) continue;   // dil=1: alpha is dead
#pragma unroll
          for (int q = 0; q < 4; q++) {
            const short8 bfr = *(const short8*)(wb8 + (size_t)((g * 4 + q) * KT + k) * 1024);
            acc[g][q] = mfma16(af, bfr, acc[g][q]);
          }
        }
      }

      // ---- cell elementwise + publish whole ----
      // lane holds cells (m = quad*4+r, col = w*64 + q*16 + lm)
      char* wb_base;
      if (w < 2) wb_base = smem + ((L & 1) ? O1_OFF : O0_OFF);
      else       wb_base = smem + HOFF[L] + (t % P) * 4096;
#pragma unroll
      for (int q = 0; q < 4; q++) {
        const int gc = w * 64 + q * 16 + lm;
        const int ch = (w < 2) ? gc : gc - 128;
        const int a0 = (ch >> 5) * 1024 + ((ch & 31) >> 3) * 256 + (ch & 7) * 2;
        f32x4 pq = pC[L][q];
        f32x4 nq;
#pragma unroll
        for (int r = 0; r < 4; r++) {
          const float fg = sigm(acc[0][q][r] + biasv[L][q]);          // +1 folded
          const float cd = tanh_(acc[1][q][r] + biasv[L][4 + q]);
          const float og = sigm(acc[3][q][r] + biasv[L][12 + q]);
          float wc;
          if constexpr (L == 0) {
            wc = pq[r];                     // alpha*pC + (1-alpha)*pC == pC
          } else {
            const float al = sigm(acc[2][q][r] + biasv[L][8 + q]);
            wc = (t >= DL) ? al * pq[r] + (1.0f - al) * dC[q][r] : pq[r];
          }
          const float nc = (t >= 1) ? fg * wc + (1.0f - fg) * cd : cd;
          nq[r] = nc;
          const float wh = og * nc;
          *(unsigned short*)(wb_base + a0 + (quad * 4 + r) * 16) = f2bf(wh);
        }
        pC[L][q] = nq;
        if constexpr (L > 0) {
          __builtin_nontemporal_store(nq, (f32x4*)(crp + q * 16));
        }
      }
    };

    do_layer(IC<0>{});
    do_layer(IC<1>{});
    do_layer(IC<2>{});
    do_layer(IC<3>{});

    // ---- y = out3 @ Wout^T + bout (out3 in O1, fragment order) ----
    __syncthreads();
    if (tid < 128) {
      const int row = tid >> 3, o = tid & 7;
      float s = 0.f;
#pragma unroll 8
      for (int c = 0; c < 128; c++) {
        const unsigned short hv = *(const unsigned short*)
            (smem + O1_OFF + (c >> 5) * 1024 + ((c & 31) >> 3) * 256 + row * 16 + (c & 7) * 2);
        s += bf2f(hv) * woutl[o * 128 + c];
      }
      __builtin_nontemporal_store(s + boutl[o],
          yout + ((size_t)t * BB + wg * 16 + row) * NO + o);
    }
  }
}

extern "C" void kernel_launch(void* const* d_in, const int* in_sizes, int n_in,
                              void* d_out, int out_size, void* d_ws, size_t ws_size,
                              hipStream_t stream) {
  const float* x    = (const float*)d_in[0];
  const float* W0   = (const float*)d_in[1];
  const float* b0   = (const float*)d_in[2];
  const float* W1   = (const float*)d_in[3];
  const float* b1   = (const float*)d_in[4];
  const float* W2   = (const float*)d_in[5];
  const float* b2   = (const float*)d_in[6];
  const float* W3   = (const float*)d_in[7];
  const float* b3   = (const float*)d_in[8];
  const float* Wout = (const float*)d_in[9];
  const float* bout = (const float*)d_in[10];
  float* out = (float*)d_out;
  char* ws = (char*)d_ws;

  if (ws_size < WS_NEED) {
    fprintf(stderr, "kernel_launch: ws_size %zu < needed %zu\n", ws_size, (size_t)WS_NEED);
    return;
  }

  unsigned short* wswz = (unsigned short*)(ws + WSWZ_OFF);
  char* cring = ws + CRING_OFF;

  prep_weights<<<dim3((NFRAG_TOT + 255) / 256), dim3(256), 0, stream>>>(
      W0, W1, W2, W3, wswz);

  hipError_t e = hipFuncSetAttribute((const void*)rnn_main,
                                     hipFuncAttributeMaxDynamicSharedMemorySize,
                                     LDS_BYTES);
  if (e != hipSuccess) fprintf(stderr, "hipFuncSetAttribute: %d\n", (int)e);

  rnn_main<<<dim3(64), dim3(256), LDS_BYTES, stream>>>(
      x, b0, b1, b2, b3, Wout, bout, wswz, cring, out);
  e = hipGetLastError();
  if (e != hipSuccess) fprintf(stderr, "launch error: %d\n", (int)e);
}

// Round 4
// 6084.752 us; speedup vs baseline: 9.2568x; 9.2568x over previous
//
#include <hip/hip_runtime.h>
#include <stdint.h>
#include <stdio.h>

// ---------------------------------------------------------------------------
// DilatedSparseRnnStack, round 4: round-1 persistent-cluster structure
// (weights LDS-resident, zero weight re-reads) with XCD-LOCAL synchronization:
//  - clusters formed at RUNTIME from HW_REG_XCC_ID + per-XCD rank atomics,
//    so all 32 WGs of a cluster share one XCD's L2 by construction.
//  - barrier: __syncthreads (drains stores to write-through L1 -> L2) +
//    L2 atomic counter + "buffer_inv sc0" (invalidate vector L1 only).
//    NO buffer_wbl2 / agent fences -> no per-phase L2 flush (round-1 killer).
// 8 clusters (128 batch rows) x 32 WGs (8 SS-cols, 96 KB weights in LDS).
// Phase = (t, layer): MFMA gates -> cell -> publish whole -> cluster barrier.
// ---------------------------------------------------------------------------

typedef __attribute__((ext_vector_type(8))) short short8;
typedef __attribute__((ext_vector_type(4))) float f32x4;

#define DEVINL static __device__ __forceinline__

constexpr int TT = 256, BBATCH = 1024, INW = 64, HSW = 128, OSW = 128, NO = 8;
constexpr int ROWS = 128;                 // batch rows per cluster

constexpr int KLa[4]   = {320, 384, 448, 384};
constexpr int DILa[4]  = {1, 3, 6, 12};
constexpr int PERa[4]  = {2, 4, 7, 13};   // h ring period = dil+1
constexpr int LDWa[4]  = {328, 392, 456, 392};            // padded LDS strides
constexpr int WOFFa[4] = {0, 10496, 23040, 37632};        // ushort offsets

constexpr int GSTRIDE = 36;
constexpr int GATES_B = 50176 * 2;                 // 100,352
constexpr int BIAS_B  = GATES_B + 128 * GSTRIDE * 4;   // 118,784
constexpr int WOUT_B  = BIAS_B + 128 * 4;              // 119,296
constexpr int WSTR    = 129;                           // wout pad (bank-conflict-free)
constexpr int BOUT_B  = WOUT_B + 8 * WSTR * 4;         // 123,424
constexpr int LDS_BYTES = BOUT_B + 32;                 // 123,456

// workspace layout (bytes)
//   [0,2048)    per-cluster barrier counters (c*256)
//   [2048,2560) per-XCD rank counters (c*64)
constexpr size_t WSBASE    = 4096;
constexpr size_t BH_OFF[4] = {0, 65536, 196608, 425984}; // h rings (P_l slots of 128x128 bf16)
constexpr size_t OUTB_OFF  = 851968;                     // 4 x 128x128 bf16
constexpr size_t CB_OFF    = 983040;                     // C rings, per (layer, wg)
constexpr size_t CB_L[4]   = {0, 131072, 524288, 1310720};
constexpr size_t CLSZ      = 3866624;
constexpr size_t WS_NEED   = WSBASE + 8 * CLSZ;          // ~29.5 MB

__host__ __device__ constexpr int seg_type(int L, int k) {
  // 0 = x (fp32), 1 = prev-layer out, 2 = prevH, 3 = dH
  if (L == 0) return k < 64 ? 0 : (k < 192 ? 2 : 3);
  if (L == 1) return k < 128 ? 1 : (k < 256 ? 2 : 3);
  if (L == 2) return k < 128 ? 1 : (k < 192 ? 0 : (k < 320 ? 2 : 3));
  return k < 128 ? 1 : (k < 256 ? 2 : 3);
}
__host__ __device__ constexpr int seg_start(int L, int k) {
  if (L == 0) return k < 64 ? 0 : (k < 192 ? 64 : 192);
  if (L == 1) return k < 128 ? 0 : (k < 256 ? 128 : 256);
  if (L == 2) return k < 128 ? 0 : (k < 192 ? 128 : (k < 320 ? 192 : 320));
  return k < 128 ? 0 : (k < 256 ? 128 : 256);
}

template <int N> struct IC { static constexpr int value = N; };

DEVINL unsigned short f2bf(float f) {        // RNE fp32 -> bf16
  union { float f; uint32_t u; } v; v.f = f;
  return (unsigned short)((v.u + 0x7FFFu + ((v.u >> 16) & 1u)) >> 16);
}
DEVINL float bf2f(unsigned short h) {
  union { uint32_t u; float f; } v; v.u = ((uint32_t)h) << 16;
  return v.f;
}
DEVINL float sigm(float x)  { return 1.0f / (1.0f + __expf(-x)); }
DEVINL float tanh_(float x) { return 1.0f - 2.0f / (__expf(2.0f * x) + 1.0f); }

DEVINL short8 zero_s8() { short8 v; for (int i = 0; i < 8; i++) v[i] = 0; return v; }
DEVINL f32x4  zero_f4() { f32x4  v; for (int i = 0; i < 4; i++) v[i] = 0.f; return v; }

DEVINL f32x4 mfma16(short8 a, short8 b, f32x4 c) {
  return __builtin_amdgcn_mfma_f32_16x16x32_bf16(a, b, c, 0, 0, 0);
}

DEVINL short8 ld8f(const float* p) {         // 8 fp32 -> bf16x8 fragment
  const f32x4 u0 = *(const f32x4*)p;
  const f32x4 u1 = *(const f32x4*)(p + 4);
  short8 r;
  r[0] = (short)f2bf(u0[0]); r[1] = (short)f2bf(u0[1]);
  r[2] = (short)f2bf(u0[2]); r[3] = (short)f2bf(u0[3]);
  r[4] = (short)f2bf(u1[0]); r[5] = (short)f2bf(u1[1]);
  r[6] = (short)f2bf(u1[2]); r[7] = (short)f2bf(u1[3]);
  return r;
}

// XCD-local cluster barrier. Correct because all 32 member WGs share this
// XCD's L2 (runtime XCC_ID grouping): stores are in L2 after the vmcnt(0)
// that __syncthreads emits (L1 is write-through); acquire only needs to
// invalidate this CU's vector L1 (buffer_inv sc0). No L2 writeback.
DEVINL void cluster_barrier(unsigned* ctr, unsigned target) {
  __syncthreads();                 // drains this WG's stores into L2
  if (threadIdx.x == 0) {
    __hip_atomic_fetch_add(ctr, 1u, __ATOMIC_RELAXED, __HIP_MEMORY_SCOPE_AGENT);
    while (__hip_atomic_load(ctr, __ATOMIC_RELAXED, __HIP_MEMORY_SCOPE_AGENT) < target)
      __builtin_amdgcn_s_sleep(1);
  }
  __syncthreads();
  asm volatile("buffer_inv sc0" ::: "memory");   // L1 invalidate (XCD-scope acquire)
}

__global__ void __launch_bounds__(256, 1)
rnn_stack_kernel(const float* __restrict__ x,
                 const float* __restrict__ W0, const float* __restrict__ b0,
                 const float* __restrict__ W1, const float* __restrict__ b1,
                 const float* __restrict__ W2, const float* __restrict__ b2,
                 const float* __restrict__ W3, const float* __restrict__ b3,
                 const float* __restrict__ Wout, const float* __restrict__ bout,
                 float* __restrict__ yout, char* __restrict__ ws)
{
  extern __shared__ char smem[];
  unsigned short* wlds = (unsigned short*)smem;
  float* gates = (float*)(smem + GATES_B);
  float* biasl = (float*)(smem + BIAS_B);
  float* woutl = (float*)(smem + WOUT_B);
  float* boutl = (float*)(smem + BOUT_B);

  const int tid = threadIdx.x;

  // ---- runtime cluster formation: c = physical XCD, g = rank on that XCD ----
  __shared__ unsigned s_cg;
  if (tid == 0) {
    unsigned xcc;
    asm volatile("s_getreg_b32 %0, hwreg(HW_REG_XCC_ID)" : "=s"(xcc));
    xcc &= 7u;
    unsigned rank = __hip_atomic_fetch_add(
        (unsigned*)(ws + 2048 + (size_t)xcc * 64), 1u,
        __ATOMIC_RELAXED, __HIP_MEMORY_SCOPE_AGENT);
    s_cg = (xcc << 8) | (rank & 31u);
  }
  __syncthreads();
  const int c = s_cg >> 8;         // cluster == XCD, owns batch rows c*128..+127
  const int g = s_cg & 255;        // column-group 0..31 (owns SS cols g*8..g*8+7)

  unsigned* ctr = (unsigned*)(ws + (size_t)c * 256);
  char* cb = ws + WSBASE + (size_t)c * CLSZ;
  unsigned short* bufH[4];
  unsigned short* outb[4];
  float* bufC[4];
#pragma unroll
  for (int l = 0; l < 4; l++) {
    bufH[l] = (unsigned short*)(cb + BH_OFF[l]);
    outb[l] = (unsigned short*)(cb + OUTB_OFF + (size_t)l * ROWS * OSW * 2);
    bufC[l] = (float*)(cb + CB_OFF + CB_L[l] +
                       (size_t)g * ((size_t)DILa[l] * ROWS * 8 * 4));
  }

  // ---- startup: weight/bias slices -> LDS (bf16) ----
  {
    const float* Wsrc[4] = {W0, W1, W2, W3};
    const float* bsrc[4] = {b0, b1, b2, b3};
    for (int l = 0; l < 4; l++) {
      const int K = KLa[l], LDW = LDWa[l];
      for (int n = 0; n < 32; n++) {
        const int grow = (n >> 3) * 256 + g * 8 + (n & 7);   // gate*SS + jglob
        const float* src = Wsrc[l] + (size_t)grow * K;
        unsigned short* dst = wlds + WOFFa[l] + n * LDW;
        for (int k = tid; k < K; k += 256) dst[k] = f2bf(src[k]);
      }
      if (tid < 32) biasl[l * 32 + tid] = bsrc[l][(tid >> 3) * 256 + g * 8 + (tid & 7)];
    }
    for (int i = tid; i < 8 * 128; i += 256) woutl[(i >> 7) * WSTR + (i & 127)] = Wout[i];
    if (tid < 8) boutl[tid] = bout[tid];
  }
  __syncthreads();

  f32x4 pc[4];                     // prevC (fp32, thread-private: 4 (row,j) per layer)
#pragma unroll
  for (int l = 0; l < 4; l++) pc[l] = zero_f4();
  unsigned phase = 0;

  const int wv = tid >> 6, lane = tid & 63, lm = lane & 15, quad = lane >> 4;
  const int m0 = wv * 32;          // wave's first batch row (2 M-tiles per wave)

  for (int t = 0; t < TT; t++) {
    auto do_layer = [&](auto Lc) {
      constexpr int L = decltype(Lc)::value;
      constexpr int K   = KLa[L];
      constexpr int NKT = K / 32;
      constexpr int DL  = DILa[L];
      constexpr int P   = PERa[L];
      constexpr int LDW = LDWa[L];
      const unsigned short* wl = wlds + WOFFa[L];
      const unsigned short* phb =
          (t >= 1) ? bufH[L] + (size_t)((t - 1) % P) * ROWS * HSW : nullptr;
      const unsigned short* dhb =
          (t >= DL) ? bufH[L] + (size_t)((t - DL) % P) * ROWS * HSW : phb;
      const unsigned short* ob = (L > 0) ? outb[L - 1] : nullptr;
      const float* xb = x + ((size_t)t * BBATCH + (size_t)c * ROWS) * INW;

      // ---- gates[128 x 32] = xh @ Wslice^T  (MFMA 16x16x32 bf16) ----
      f32x4 acc00 = zero_f4(), acc01 = zero_f4(), acc10 = zero_f4(), acc11 = zero_f4();
#pragma unroll
      for (int kt = 0; kt < NKT; kt++) {
        const int sty  = seg_type(L, kt * 32);    // folds at compile time
        const int sst  = seg_start(L, kt * 32);
        const int kloc = kt * 32 - sst + quad * 8;
        short8 a0, a1;
        if (sty == 0) {
          const float* p = xb + (size_t)(m0 + lm) * INW + kloc;
          a0 = ld8f(p);
          a1 = ld8f(p + 16 * INW);
        } else {
          const unsigned short* sb = (sty == 1) ? ob : ((sty == 2) ? phb : dhb);
          if (sb) {
            const unsigned short* p = sb + (size_t)(m0 + lm) * HSW + kloc;
            a0 = *(const short8*)p;
            a1 = *(const short8*)(p + 16 * HSW);
          } else {
            a0 = zero_s8();
            a1 = zero_s8();
          }
        }
        const short8 bf0 = *(const short8*)(wl + (size_t)lm * LDW + kt * 32 + quad * 8);
        const short8 bf1 = *(const short8*)(wl + (size_t)(16 + lm) * LDW + kt * 32 + quad * 8);
        acc00 = mfma16(a0, bf0, acc00);
        acc01 = mfma16(a0, bf1, acc01);
        acc10 = mfma16(a1, bf0, acc10);
        acc11 = mfma16(a1, bf1, acc11);
      }
      // C-layout: col = lane&15, row = quad*4 + reg  (m89-verified)
#pragma unroll
      for (int r = 0; r < 4; r++) {
        gates[(m0 + quad * 4 + r) * GSTRIDE + lm]           = acc00[r];
        gates[(m0 + quad * 4 + r) * GSTRIDE + 16 + lm]      = acc01[r];
        gates[(m0 + 16 + quad * 4 + r) * GSTRIDE + lm]      = acc10[r];
        gates[(m0 + 16 + quad * 4 + r) * GSTRIDE + 16 + lm] = acc11[r];
      }
      __syncthreads();

      // ---- cell elementwise: thread owns (row = tid&127, j0 = (tid>>7)*4 .. +3) ----
      {
        const int row = tid & 127, j0 = (tid >> 7) * 4;
        const f32x4 G0 = *(const f32x4*)&gates[row * GSTRIDE + 0 + j0];
        const f32x4 G1 = *(const f32x4*)&gates[row * GSTRIDE + 8 + j0];
        const f32x4 G2 = *(const f32x4*)&gates[row * GSTRIDE + 16 + j0];
        const f32x4 G3 = *(const f32x4*)&gates[row * GSTRIDE + 24 + j0];
        float* cs = bufC[L] + ((size_t)(t % DL) * ROWS + row) * 8 + j0;
        f32x4 dC = zero_f4();
        if (t >= DL) dC = *(const f32x4*)cs;    // C from t-dil (WG-private)
        const f32x4 pcv = pc[L];
        f32x4 nC, wh;
#pragma unroll
        for (int q = 0; q < 4; q++) {
          const float fg = sigm(G0[q] + biasl[L * 32 + 0  + j0 + q] + 1.0f);
          const float cd = tanh_(G1[q] + biasl[L * 32 + 8  + j0 + q]);
          const float al = sigm(G2[q] + biasl[L * 32 + 16 + j0 + q]);
          const float og = sigm(G3[q] + biasl[L * 32 + 24 + j0 + q]);
          const float wc = (t >= DL) ? (al * pcv[q] + (1.0f - al) * dC[q]) : pcv[q];
          const float nc = (t >= 1) ? (fg * wc + (1.0f - fg) * cd) : cd;
          nC[q] = nc;
          wh[q] = og * nc;
        }
        *(f32x4*)cs = nC;           // C ring slot t%dil (read at t+dil)
        pc[L] = nC;
        ushort4 wb;
        wb.x = f2bf(wh[0]); wb.y = f2bf(wh[1]); wb.z = f2bf(wh[2]); wb.w = f2bf(wh[3]);
        const int jg = g * 8 + j0;
        if (g < 16) {               // whole[:, :128] -> next-layer input
          *(ushort4*)(outb[L] + (size_t)row * OSW + jg) = wb;
        } else {                    // whole[:, 128:] -> h ring slot t%(dil+1)
          *(ushort4*)(bufH[L] + ((size_t)(t % P) * ROWS + row) * HSW + (jg - 128)) = wb;
        }
      }
      phase++;
      cluster_barrier(ctr, 32u * phase);
    };
    do_layer(IC<0>{});
    do_layer(IC<1>{});
    do_layer(IC<2>{});
    do_layer(IC<3>{});

    // ---- y = out3 @ Wout^T + bout; wave w -> row g*4+w, 8 lanes per (r,o) ----
    {
      const int o = (tid >> 3) & 7;
      const int s = tid & 7;
      const int r = g * 4 + (tid >> 6);
      const unsigned short* orow = outb[3] + (size_t)r * OSW;
      float part = 0.f;
#pragma unroll
      for (int i = 0; i < 16; i++) {
        const int k = s * 16 + i;
        part += bf2f(orow[k]) * woutl[o * WSTR + k];
      }
      part += __shfl_down(part, 4);
      part += __shfl_down(part, 2);
      part += __shfl_down(part, 1);
      if (s == 0)
        yout[((size_t)t * BBATCH + (size_t)c * ROWS + r) * NO + o] = part + boutl[o];
    }
  }
}

extern "C" void kernel_launch(void* const* d_in, const int* in_sizes, int n_in,
                              void* d_out, int out_size, void* d_ws, size_t ws_size,
                              hipStream_t stream) {
  const float* x    = (const float*)d_in[0];
  const float* W0   = (const float*)d_in[1];
  const float* b0   = (const float*)d_in[2];
  const float* W1   = (const float*)d_in[3];
  const float* b1   = (const float*)d_in[4];
  const float* W2   = (const float*)d_in[5];
  const float* b2   = (const float*)d_in[6];
  const float* W3   = (const float*)d_in[7];
  const float* b3   = (const float*)d_in[8];
  const float* Wout = (const float*)d_in[9];
  const float* bout = (const float*)d_in[10];
  float* out = (float*)d_out;
  char* ws = (char*)d_ws;

  if (ws_size < WS_NEED) {
    fprintf(stderr, "kernel_launch: ws_size %zu < needed %zu\n", ws_size, (size_t)WS_NEED);
    return;
  }

  // zero barrier + rank counters (ws is poisoned 0xAA before every launch)
  hipMemsetAsync(d_ws, 0, 4096, stream);

  hipError_t e = hipFuncSetAttribute((const void*)rnn_stack_kernel,
                                     hipFuncAttributeMaxDynamicSharedMemorySize,
                                     LDS_BYTES);
  if (e != hipSuccess) fprintf(stderr, "hipFuncSetAttribute: %d\n", (int)e);

  rnn_stack_kernel<<<dim3(256), dim3(256), LDS_BYTES, stream>>>(
      x, W0, b0, W1, b1, W2, b2, W3, b3, Wout, bout, out, ws);
  e = hipGetLastError();
  if (e != hipSuccess) fprintf(stderr, "launch error: %d\n", (int)e);
}